// Round 5
// baseline (476.270 us; speedup 1.0000x reference)
//
#include <hip/hip_runtime.h>

#define EMB 16
typedef unsigned int u32;

__global__ void zero_f32(float* __restrict__ p, size_t n) {
    size_t i = (size_t)blockIdx.x * blockDim.x + threadIdx.x;
    size_t stride = (size_t)gridDim.x * blockDim.x;
    for (; i < n; i += stride) p[i] = 0.0f;
}

__global__ void zero_i32(int* __restrict__ p, int n) {
    int i = blockIdx.x * blockDim.x + threadIdx.x;
    if (i < n) p[i] = 0;
}

__device__ __forceinline__ u32 bf16bits_rne(float x) {
    u32 u = __float_as_uint(x);
    return (u + 0x7fffu + ((u >> 16) & 1u)) >> 16;
}

// Packed bf16 linear: Ypk[row*8+h] = pack(bf16(row@W[:,h+8]+b), bf16(row@W[:,h]+b))
// One thread per (row, h), h in [0,8).
__global__ void linear16_pack_kernel(const float* __restrict__ X, const float* __restrict__ W,
                                     const float* __restrict__ b, u32* __restrict__ Y, int N) {
    int tid = blockIdx.x * blockDim.x + threadIdx.x;
    int row = tid >> 3;
    int h = tid & 7;
    if (row >= N) return;
    float a0 = b ? b[h] : 0.0f;
    float a1 = b ? b[h + 8] : 0.0f;
    const float* xr = X + (size_t)row * EMB;
#pragma unroll
    for (int k = 0; k < EMB; ++k) {
        float xv = xr[k];
        a0 = fmaf(xv, W[k * EMB + h], a0);
        a1 = fmaf(xv, W[k * EMB + h + 8], a1);
    }
    Y[(size_t)row * 8 + h] = (bf16bits_rne(a1) << 16) | bf16bits_rne(a0);
}

// One 8-lane group per edge; lane h handles components h and h+8.
// S[r,j] += relu(L[l,j] + ef[e]*We[j] + R[r,j]);  cnt[r] += 1 (lane 0).
__global__ void edge_kernel(const int* __restrict__ eidx, const float* __restrict__ ef,
                            const u32* __restrict__ Lpk, const u32* __restrict__ Rpk,
                            const float* __restrict__ We, float* __restrict__ S,
                            int* __restrict__ cnt, int E) {
    long long tid = (long long)blockIdx.x * blockDim.x + threadIdx.x;
    int e = (int)(tid >> 3);
    int h = (int)(tid & 7);
    if (e >= E) return;
    int l = eidx[e];
    int r = eidx[E + e];
    float f = ef[e];
    u32 lp = Lpk[(size_t)l * 8 + h];
    u32 rp = Rpk[(size_t)r * 8 + h];
    float l0 = __uint_as_float(lp << 16);
    float l1 = __uint_as_float(lp & 0xffff0000u);
    float r0 = __uint_as_float(rp << 16);
    float r1 = __uint_as_float(rp & 0xffff0000u);
    float v0 = fmaxf(fmaf(f, We[h], l0) + r0, 0.0f);
    float v1 = fmaxf(fmaf(f, We[h + 8], l1) + r1, 0.0f);
    unsafeAtomicAdd(&S[(size_t)r * EMB + h], v0);
    unsafeAtomicAdd(&S[(size_t)r * EMB + h + 8], v1);
    if (h == 0) atomicAdd(&cnt[r], 1);
}

// ---------------- per-node epilogue ----------------
// agg = S@Wf + deg*bf ; post = relu(agg)@Wp + bp ; h=[post, rf] ;
// out = relu(h@Wo1 + bo1)@Wo2 + bo2.  One thread per node.
__global__ void final_kernel(const float* __restrict__ S, const int* __restrict__ deg,
                             const float* __restrict__ rf,
                             const float* __restrict__ Wf, const float* __restrict__ bf,
                             const float* __restrict__ Wp, const float* __restrict__ bp,
                             const float* __restrict__ Wo1, const float* __restrict__ bo1,
                             const float* __restrict__ Wo2, const float* __restrict__ bo2,
                             float* __restrict__ out, int N) {
    __shared__ float sWf[256], sWp[256], sWo1[512], sWo2[256];
    __shared__ float sb[64];  // [bf | bp | bo1 | bo2]
    int t = threadIdx.x;
    for (int i = t; i < 256; i += 256) { sWf[i] = Wf[i]; sWp[i] = Wp[i]; sWo2[i] = Wo2[i]; }
    for (int i = t; i < 512; i += 256) sWo1[i] = Wo1[i];
    if (t < 16) { sb[t] = bf[t]; sb[16 + t] = bp[t]; sb[32 + t] = bo1[t]; sb[48 + t] = bo2[t]; }
    __syncthreads();

    int r = blockIdx.x * blockDim.x + t;
    if (r >= N) return;

    float s[16], x[16], y[16], rv[16], z[16], o[16];
    const float4* Sp = (const float4*)(S + (size_t)r * EMB);
    const float4* Rp = (const float4*)(rf + (size_t)r * EMB);
#pragma unroll
    for (int k = 0; k < 4; ++k) {
        float4 v = Sp[k];
        s[4 * k] = v.x; s[4 * k + 1] = v.y; s[4 * k + 2] = v.z; s[4 * k + 3] = v.w;
        float4 w = Rp[k];
        rv[4 * k] = w.x; rv[4 * k + 1] = w.y; rv[4 * k + 2] = w.z; rv[4 * k + 3] = w.w;
    }
    float c = (float)deg[r];

#pragma unroll
    for (int j = 0; j < 16; ++j) {
        float a = c * sb[j];
#pragma unroll
        for (int k = 0; k < 16; ++k) a = fmaf(s[k], sWf[k * 16 + j], a);
        x[j] = fmaxf(a, 0.0f);
    }
#pragma unroll
    for (int j = 0; j < 16; ++j) {
        float a = sb[16 + j];
#pragma unroll
        for (int k = 0; k < 16; ++k) a = fmaf(x[k], sWp[k * 16 + j], a);
        y[j] = a;
    }
#pragma unroll
    for (int j = 0; j < 16; ++j) {
        float a = sb[32 + j];
#pragma unroll
        for (int k = 0; k < 16; ++k) a = fmaf(y[k], sWo1[k * 16 + j], a);
#pragma unroll
        for (int k = 0; k < 16; ++k) a = fmaf(rv[k], sWo1[(16 + k) * 16 + j], a);
        z[j] = fmaxf(a, 0.0f);
    }
#pragma unroll
    for (int j = 0; j < 16; ++j) {
        float a = sb[48 + j];
#pragma unroll
        for (int k = 0; k < 16; ++k) a = fmaf(z[k], sWo2[k * 16 + j], a);
        o[j] = a;
    }
    float4* Op = (float4*)(out + (size_t)r * EMB);
#pragma unroll
    for (int k = 0; k < 4; ++k)
        Op[k] = make_float4(o[4 * k], o[4 * k + 1], o[4 * k + 2], o[4 * k + 3]);
}

extern "C" void kernel_launch(void* const* d_in, const int* in_sizes, int n_in,
                              void* d_out, int out_size, void* d_ws, size_t ws_size,
                              hipStream_t stream) {
    const float* lf     = (const float*)d_in[0];
    const int*   eidx   = (const int*)d_in[1];
    const float* ef     = (const float*)d_in[2];
    const float* rf     = (const float*)d_in[3];
    const float* W_left = (const float*)d_in[4];
    const float* b_left = (const float*)d_in[5];
    const float* W_edge = (const float*)d_in[6];
    const float* W_right= (const float*)d_in[7];
    const float* W_final= (const float*)d_in[8];
    const float* b_final= (const float*)d_in[9];
    const float* W_post = (const float*)d_in[10];
    const float* b_post = (const float*)d_in[11];
    const float* W_out1 = (const float*)d_in[12];
    const float* b_out1 = (const float*)d_in[13];
    const float* W_out2 = (const float*)d_in[14];
    const float* b_out2 = (const float*)d_in[15];

    int n_left  = in_sizes[0] / EMB;
    int E       = in_sizes[2];
    int n_right = in_sizes[3] / EMB;
    float* out = (float*)d_out;

    u32*   Lpk = (u32*)d_ws;
    u32*   Rpk = Lpk + (size_t)n_left * 8;
    float* S   = (float*)(Rpk + (size_t)n_right * 8);
    int*   cnt = (int*)(S + (size_t)n_right * EMB);

    zero_f32<<<2048, 256, 0, stream>>>(S, (size_t)n_right * EMB);
    zero_i32<<<(n_right + 255) / 256, 256, 0, stream>>>(cnt, n_right);

    linear16_pack_kernel<<<(n_left * 8 + 255) / 256, 256, 0, stream>>>(lf, W_left, b_left, Lpk, n_left);
    linear16_pack_kernel<<<(n_right * 8 + 255) / 256, 256, 0, stream>>>(rf, W_right, nullptr, Rpk, n_right);

    long long ethreads = (long long)E * 8;
    edge_kernel<<<(unsigned)((ethreads + 255) / 256), 256, 0, stream>>>(eidx, ef, Lpk, Rpk, W_edge, S, cnt, E);

    final_kernel<<<(n_right + 255) / 256, 256, 0, stream>>>(S, cnt, rf,
        W_final, b_final, W_post, b_post, W_out1, b_out1, W_out2, b_out2, out, n_right);
}

// Round 6
// 433.144 us; speedup vs baseline: 1.0996x; 1.0996x over previous
//
#include <hip/hip_runtime.h>

#define EMB 16
#define BSH 7                 // 128 right-nodes per bucket
#define BNODES 128
#define MAXNB 1024
#define PCHUNK 16384
#define STRD 17               // padded LDS row stride (bank-conflict break)
typedef unsigned int u32;
typedef unsigned long long u64;

__global__ void zero_f32(float* __restrict__ p, size_t n) {
    size_t i = (size_t)blockIdx.x * blockDim.x + threadIdx.x;
    size_t stride = (size_t)gridDim.x * blockDim.x;
    for (; i < n; i += stride) p[i] = 0.0f;
}

__global__ void zero_i32(int* __restrict__ p, int n) {
    int i = blockIdx.x * blockDim.x + threadIdx.x;
    if (i < n) p[i] = 0;
}

__device__ __forceinline__ u32 bf16bits_rne(float x) {
    u32 u = __float_as_uint(x);
    return (u + 0x7fffu + ((u >> 16) & 1u)) >> 16;
}

// Packed bf16 linear: Y[row*8+h] = pack(bf16(row@W[:,h+8]+b), bf16(row@W[:,h]+b))
__global__ void linear16_pack_kernel(const float* __restrict__ X, const float* __restrict__ W,
                                     const float* __restrict__ b, u32* __restrict__ Y, int N) {
    int tid = blockIdx.x * blockDim.x + threadIdx.x;
    int row = tid >> 3;
    int h = tid & 7;
    if (row >= N) return;
    float a0 = b ? b[h] : 0.0f;
    float a1 = b ? b[h + 8] : 0.0f;
    const float* xr = X + (size_t)row * EMB;
#pragma unroll
    for (int k = 0; k < EMB; ++k) {
        float xv = xr[k];
        a0 = fmaf(xv, W[k * EMB + h], a0);
        a1 = fmaf(xv, W[k * EMB + h + 8], a1);
    }
    Y[(size_t)row * 8 + h] = (bf16bits_rne(a1) << 16) | bf16bits_rne(a0);
}

// Plain f32 linear (fallback path)
__global__ void linear16_kernel(const float* __restrict__ X, const float* __restrict__ W,
                                const float* __restrict__ b, float* __restrict__ Y, int N) {
    int tid = blockIdx.x * blockDim.x + threadIdx.x;
    int row = tid >> 4;
    int j = tid & 15;
    if (row >= N) return;
    float acc = b ? b[j] : 0.0f;
    const float* xr = X + (size_t)row * EMB;
#pragma unroll
    for (int k = 0; k < EMB; ++k) acc = fmaf(xr[k], W[k * EMB + j], acc);
    Y[(size_t)row * EMB + j] = acc;
}

// ---------------- bucket CSR build ----------------

__global__ void bucket_hist_kernel(const int* __restrict__ ridx, int* __restrict__ bhist,
                                   int E, int NB) {
    __shared__ int h[MAXNB];
    int t = threadIdx.x;
    for (int i = t; i < NB; i += 256) h[i] = 0;
    __syncthreads();
    int idx = blockIdx.x * blockDim.x + t;
    int stride = gridDim.x * blockDim.x;
    for (int e = idx; e < E; e += stride) atomicAdd(&h[ridx[e] >> BSH], 1);
    __syncthreads();
    for (int i = t; i < NB; i += 256) if (h[i]) atomicAdd(&bhist[i], h[i]);
}

__global__ void bucket_scan_kernel(const int* __restrict__ bhist, int* __restrict__ boff,
                                   int* __restrict__ gcur, int NB) {
    __shared__ int sc[1024];
    int t = threadIdx.x;
    int v = (t < NB) ? bhist[t] : 0;
    sc[t] = v;
    __syncthreads();
    for (int d = 1; d < 1024; d <<= 1) {
        int x = (t >= d) ? sc[t - d] : 0;
        __syncthreads();
        sc[t] += x;
        __syncthreads();
    }
    int excl = sc[t] - v;
    if (t < NB) { boff[t] = excl; gcur[t] = excl; }
    if (t == 1023) boff[NB] = sc[1023];
}

// Two-pass partition: LDS hist -> one aggregated global reservation per bucket
// -> clustered scatter of packed records [f:32][l:24][rl:7].
__launch_bounds__(512)
__global__ void partition_kernel(const int* __restrict__ eidx, const float* __restrict__ ef,
                                 int* __restrict__ gcur, u64* __restrict__ rec, int E, int NB) {
    __shared__ int hist[MAXNB];
    __shared__ int lbase[MAXNB];
    int t = threadIdx.x;
    long long base = (long long)blockIdx.x * PCHUNK;
    int n = (int)((E - base) < PCHUNK ? (E - base) : PCHUNK);
    const int* ridx = eidx + E;
    for (int i = t; i < NB; i += 512) hist[i] = 0;
    __syncthreads();
    for (int i = t; i < n; i += 512) atomicAdd(&hist[ridx[base + i] >> BSH], 1);
    __syncthreads();
    for (int i = t; i < NB; i += 512) {
        int h = hist[i];
        lbase[i] = h ? atomicAdd(&gcur[i], h) : 0;
        hist[i] = 0;  // reuse as local cursor
    }
    __syncthreads();
    for (int i = t; i < n; i += 512) {
        int r = ridx[base + i];
        int b = r >> BSH;
        int l = eidx[base + i];
        float f = ef[base + i];
        int pos = lbase[b] + atomicAdd(&hist[b], 1);
        rec[pos] = ((u64)__float_as_uint(f) << 32) | ((u64)(u32)l << BSH) | (u32)(r & (BNODES - 1));
    }
}

// ---------------- gather: one block per 128-node bucket, native LDS fp atomics ----
__launch_bounds__(512)
__global__ void bucket_gather_kernel(const u64* __restrict__ rec, const int* __restrict__ boff,
                                     const u32* __restrict__ Lpk, const u32* __restrict__ Rpk,
                                     const float* __restrict__ We,
                                     float* __restrict__ S, int* __restrict__ deg, int n_right) {
    __shared__ float Stile[BNODES * STRD];
    __shared__ int dtile[BNODES];
    int b = blockIdx.x;
    int t = threadIdx.x;
    int node0 = b << BSH;
    int nn = n_right - node0; if (nn > BNODES) nn = BNODES;

    for (int i = t; i < BNODES * STRD; i += 512) Stile[i] = 0.0f;
    for (int i = t; i < BNODES; i += 512) dtile[i] = 0;
    __syncthreads();

    int h = t & 7;
    int sub = t >> 3;  // 0..63 record slots
    float we0 = We[h], we1 = We[h + 8];
    int start = boff[b], end = boff[b + 1];
    for (int i = start + sub; i < end; i += 64) {
        u64 rc = rec[i];
        int rl = (int)(rc & (u32)(BNODES - 1));
        int l  = (int)((rc >> BSH) & 0xFFFFFFu);
        float f = __uint_as_float((u32)(rc >> 32));
        u32 lp = Lpk[(size_t)l * 8 + h];
        u32 rp = Rpk[(size_t)(node0 + rl) * 8 + h];
        float v0 = fmaxf(fmaf(f, we0, __uint_as_float(lp << 16)) + __uint_as_float(rp << 16), 0.0f);
        float v1 = fmaxf(fmaf(f, we1, __uint_as_float(lp & 0xffff0000u)) + __uint_as_float(rp & 0xffff0000u), 0.0f);
        unsafeAtomicAdd(&Stile[rl * STRD + h], v0);
        unsafeAtomicAdd(&Stile[rl * STRD + h + 8], v1);
        if (h == 0) atomicAdd(&dtile[rl], 1);
    }
    __syncthreads();
    for (int i = t; i < nn * EMB; i += 512) {
        int node = i >> 4, c = i & 15;
        S[(size_t)(node0 + node) * EMB + c] = Stile[node * STRD + c];
    }
    for (int i = t; i < nn; i += 512) deg[node0 + i] = dtile[i];
}

// ---------------- fallback atomic edge kernel (f32 tables) ----------------
__global__ void edge_kernel(const int* __restrict__ eidx, const float* __restrict__ ef,
                            const float* __restrict__ L, const float* __restrict__ R,
                            const float* __restrict__ We, float* __restrict__ S,
                            int* __restrict__ cnt, int E) {
    long long tid = (long long)blockIdx.x * blockDim.x + threadIdx.x;
    int e = (int)(tid >> 4);
    int j = (int)(tid & 15);
    if (e >= E) return;
    int l = eidx[e];
    int r = eidx[E + e];
    float v = L[(size_t)l * EMB + j] + ef[e] * We[j] + R[(size_t)r * EMB + j];
    v = fmaxf(v, 0.0f);
    unsafeAtomicAdd(&S[(size_t)r * EMB + j], v);
    if (j == 0) atomicAdd(&cnt[r], 1);
}

// ---------------- per-node epilogue ----------------
__global__ void final_kernel(const float* __restrict__ S, const int* __restrict__ deg,
                             const float* __restrict__ rf,
                             const float* __restrict__ Wf, const float* __restrict__ bf,
                             const float* __restrict__ Wp, const float* __restrict__ bp,
                             const float* __restrict__ Wo1, const float* __restrict__ bo1,
                             const float* __restrict__ Wo2, const float* __restrict__ bo2,
                             float* __restrict__ out, int N) {
    __shared__ float sWf[256], sWp[256], sWo1[512], sWo2[256];
    __shared__ float sb[64];
    int t = threadIdx.x;
    for (int i = t; i < 256; i += 256) { sWf[i] = Wf[i]; sWp[i] = Wp[i]; sWo2[i] = Wo2[i]; }
    for (int i = t; i < 512; i += 256) sWo1[i] = Wo1[i];
    if (t < 16) { sb[t] = bf[t]; sb[16 + t] = bp[t]; sb[32 + t] = bo1[t]; sb[48 + t] = bo2[t]; }
    __syncthreads();

    int r = blockIdx.x * blockDim.x + t;
    if (r >= N) return;

    float s[16], x[16], y[16], rv[16], z[16], o[16];
    const float4* Sp = (const float4*)(S + (size_t)r * EMB);
    const float4* Rp = (const float4*)(rf + (size_t)r * EMB);
#pragma unroll
    for (int k = 0; k < 4; ++k) {
        float4 v = Sp[k];
        s[4 * k] = v.x; s[4 * k + 1] = v.y; s[4 * k + 2] = v.z; s[4 * k + 3] = v.w;
        float4 w = Rp[k];
        rv[4 * k] = w.x; rv[4 * k + 1] = w.y; rv[4 * k + 2] = w.z; rv[4 * k + 3] = w.w;
    }
    float c = (float)deg[r];

#pragma unroll
    for (int j = 0; j < 16; ++j) {
        float a = c * sb[j];
#pragma unroll
        for (int k = 0; k < 16; ++k) a = fmaf(s[k], sWf[k * 16 + j], a);
        x[j] = fmaxf(a, 0.0f);
    }
#pragma unroll
    for (int j = 0; j < 16; ++j) {
        float a = sb[16 + j];
#pragma unroll
        for (int k = 0; k < 16; ++k) a = fmaf(x[k], sWp[k * 16 + j], a);
        y[j] = a;
    }
#pragma unroll
    for (int j = 0; j < 16; ++j) {
        float a = sb[32 + j];
#pragma unroll
        for (int k = 0; k < 16; ++k) a = fmaf(y[k], sWo1[k * 16 + j], a);
#pragma unroll
        for (int k = 0; k < 16; ++k) a = fmaf(rv[k], sWo1[(16 + k) * 16 + j], a);
        z[j] = fmaxf(a, 0.0f);
    }
#pragma unroll
    for (int j = 0; j < 16; ++j) {
        float a = sb[48 + j];
#pragma unroll
        for (int k = 0; k < 16; ++k) a = fmaf(z[k], sWo2[k * 16 + j], a);
        o[j] = a;
    }
    float4* Op = (float4*)(out + (size_t)r * EMB);
#pragma unroll
    for (int k = 0; k < 4; ++k)
        Op[k] = make_float4(o[4 * k], o[4 * k + 1], o[4 * k + 2], o[4 * k + 3]);
}

extern "C" void kernel_launch(void* const* d_in, const int* in_sizes, int n_in,
                              void* d_out, int out_size, void* d_ws, size_t ws_size,
                              hipStream_t stream) {
    const float* lf     = (const float*)d_in[0];
    const int*   eidx   = (const int*)d_in[1];
    const float* ef     = (const float*)d_in[2];
    const float* rf     = (const float*)d_in[3];
    const float* W_left = (const float*)d_in[4];
    const float* b_left = (const float*)d_in[5];
    const float* W_edge = (const float*)d_in[6];
    const float* W_right= (const float*)d_in[7];
    const float* W_final= (const float*)d_in[8];
    const float* b_final= (const float*)d_in[9];
    const float* W_post = (const float*)d_in[10];
    const float* b_post = (const float*)d_in[11];
    const float* W_out1 = (const float*)d_in[12];
    const float* b_out1 = (const float*)d_in[13];
    const float* W_out2 = (const float*)d_in[14];
    const float* b_out2 = (const float*)d_in[15];

    int n_left  = in_sizes[0] / EMB;
    int E       = in_sizes[2];
    int n_right = in_sizes[3] / EMB;
    float* out = (float*)d_out;

    int NB = (n_right + BNODES - 1) >> BSH;

    size_t need = (size_t)E * 8
                + ((size_t)n_left + (size_t)n_right) * 8 * 4   // Lpk, Rpk
                + (size_t)n_right * EMB * 4                    // S
                + (size_t)n_right * 4                          // deg
                + (size_t)(3 * MAXNB + 2) * 4;

    if (ws_size >= need && NB <= MAXNB) {
        u64* rec   = (u64*)d_ws;
        u32* Lpk   = (u32*)(rec + (size_t)E);
        u32* Rpk   = Lpk + (size_t)n_left * 8;
        float* S   = (float*)(Rpk + (size_t)n_right * 8);
        int* deg   = (int*)(S + (size_t)n_right * EMB);
        int* bhist = deg + n_right;
        int* boff  = bhist + MAXNB;      // NB+1 entries
        int* gcur  = boff + MAXNB + 1;

        zero_i32<<<(NB + 255) / 256, 256, 0, stream>>>(bhist, NB);
        linear16_pack_kernel<<<(n_left * 8 + 255) / 256, 256, 0, stream>>>(lf, W_left, b_left, Lpk, n_left);
        linear16_pack_kernel<<<(n_right * 8 + 255) / 256, 256, 0, stream>>>(rf, W_right, nullptr, Rpk, n_right);

        bucket_hist_kernel<<<512, 256, 0, stream>>>(eidx + E, bhist, E, NB);
        bucket_scan_kernel<<<1, 1024, 0, stream>>>(bhist, boff, gcur, NB);

        int nchunks = (E + PCHUNK - 1) / PCHUNK;
        partition_kernel<<<nchunks, 512, 0, stream>>>(eidx, ef, gcur, rec, E, NB);

        bucket_gather_kernel<<<NB, 512, 0, stream>>>(rec, boff, Lpk, Rpk, W_edge, S, deg, n_right);

        final_kernel<<<(n_right + 255) / 256, 256, 0, stream>>>(S, deg, rf,
            W_final, b_final, W_post, b_post, W_out1, b_out1, W_out2, b_out2, out, n_right);
    } else {
        float* L   = (float*)d_ws;
        float* R   = L + (size_t)n_left * EMB;
        float* S   = R + (size_t)n_right * EMB;
        int*   cnt = (int*)(S + (size_t)n_right * EMB);

        zero_f32<<<2048, 256, 0, stream>>>(S, (size_t)n_right * EMB);
        zero_i32<<<(n_right + 255) / 256, 256, 0, stream>>>(cnt, n_right);

        linear16_kernel<<<(n_left * EMB + 255) / 256, 256, 0, stream>>>(lf, W_left, b_left, L, n_left);
        linear16_kernel<<<(n_right * EMB + 255) / 256, 256, 0, stream>>>(rf, W_right, nullptr, R, n_right);

        long long ethreads = (long long)E * EMB;
        edge_kernel<<<(unsigned)((ethreads + 255) / 256), 256, 0, stream>>>(eidx, ef, L, R, W_edge, S, cnt, E);

        final_kernel<<<(n_right + 255) / 256, 256, 0, stream>>>(S, cnt, rf,
            W_final, b_final, W_post, b_post, W_out1, b_out1, W_out2, b_out2, out, n_right);
    }
}